// Round 9
// baseline (469.943 us; speedup 1.0000x reference)
//
#include <hip/hip_runtime.h>
#include <cstdint>
#include <cstddef>

#define E_DIM   1024
#define B_DIM   1024
#define T_STEPS 10
#define OUT_DIM 34
#define OUT_PAD 48
#define EK      128                 // k-elements per eighth
#define WSL_ELEMS (128 * EK)        // 16384 elems = 32 KB per eighth-slice buffer
#define DYN_LDS (2 * WSL_ELEMS * 2) // 65536 B

typedef __attribute__((ext_vector_type(4))) float  f32x4;
typedef __attribute__((ext_vector_type(8))) __bf16 bf16x8;

__device__ __forceinline__ unsigned short f2bf(float f) {
    unsigned int u = __float_as_uint(f);
    u = (u + 0x7FFFu + ((u >> 16) & 1u)) >> 16;   // round-to-nearest-even
    return (unsigned short)u;
}
__device__ __forceinline__ float sigmoid_(float x) { return 1.0f / (1.0f + __expf(-x)); }
__device__ __forceinline__ float tanh_(float x)    { return 2.0f / (1.0f + __expf(-2.0f * x)) - 1.0f; }

// Weights in MFMA-B-fragment order:
//   WF[bn2(32)][E8(8)][ks8(4)][sub(8)][lane(64)][8]
// sub = wn*2+nt; decode: gate = 2*(wn&1)+nt, eb = 2*bn2 + (wn>>1);
// frag elem (lane=(q,j)): W[gate*1024 + eb*16 + j][E8*128 + ks8*32 + q*8 + e8].
// Two-phase: coalesced global read -> LDS transpose -> coalesced fragment store.
__global__ __launch_bounds__(512) void prep_weights_frag(
    const float* __restrict__ W_ih, const float* __restrict__ W_hh,
    unsigned short* __restrict__ WsumF, unsigned short* __restrict__ WhhF) {
    __shared__ unsigned short Ls[128 * 136];       // 34 KB, padded rows

    const int bn2 = blockIdx.x >> 3, E8 = blockIdx.x & 7;
    const int tid = threadIdx.x;

    // phase 1: load + convert. thread -> (row rl = tid>>2, s = tid&3), 32 floats each.
    const int rl = tid >> 2, s = tid & 3;
    const int sub_r = rl >> 4, jr = rl & 15;
    const int g_r  = 2 * ((sub_r >> 1) & 1) + (sub_r & 1);
    const int eb_r = 2 * bn2 + (sub_r >> 2);
    const size_t grow = ((size_t)g_r * E_DIM + eb_r * 16 + jr) * E_DIM + E8 * 128;
    unsigned short hhreg[32];
#pragma unroll
    for (int u = 0; u < 8; ++u) {
        const int kl = u * 16 + s * 4;
        float4 wi = *(const float4*)(W_ih + grow + kl);
        float4 wh = *(const float4*)(W_hh + grow + kl);
        Ls[rl * 136 + kl + 0] = f2bf(wi.x + wh.x);
        Ls[rl * 136 + kl + 1] = f2bf(wi.y + wh.y);
        Ls[rl * 136 + kl + 2] = f2bf(wi.z + wh.z);
        Ls[rl * 136 + kl + 3] = f2bf(wi.w + wh.w);
        hhreg[u * 4 + 0] = f2bf(wh.x);
        hhreg[u * 4 + 1] = f2bf(wh.y);
        hhreg[u * 4 + 2] = f2bf(wh.z);
        hhreg[u * 4 + 3] = f2bf(wh.w);
    }
    __syncthreads();
    // phase 2: Wsum fragment-order store (linear in tid -> coalesced)
    const size_t dstb = (size_t)bn2 * 131072 + (size_t)E8 * 16384;
#pragma unroll
    for (int i = 0; i < 4; ++i) {
        const int u4 = i * 512 + tid;              // 0..2047 8-elem units in this eighth
        const int ks8 = u4 >> 9, sb = (u4 >> 6) & 7, ln = u4 & 63;
        const int row = sb * 16 + (ln & 15), kl = ks8 * 32 + (ln >> 4) * 8;
        *(uint4*)(WsumF + dstb + (size_t)u4 * 8) = *(const uint4*)(Ls + row * 136 + kl);
    }
    __syncthreads();
    // phase 3: restage hh into Ls (scalar-safe 4-element stores), then Whh store
#pragma unroll
    for (int u = 0; u < 8; ++u) {
        const int kl = u * 16 + s * 4;
        Ls[rl * 136 + kl + 0] = hhreg[u * 4 + 0];
        Ls[rl * 136 + kl + 1] = hhreg[u * 4 + 1];
        Ls[rl * 136 + kl + 2] = hhreg[u * 4 + 2];
        Ls[rl * 136 + kl + 3] = hhreg[u * 4 + 3];
    }
    __syncthreads();
#pragma unroll
    for (int i = 0; i < 4; ++i) {
        const int u4 = i * 512 + tid;
        const int ks8 = u4 >> 9, sb = (u4 >> 6) & 7, ln = u4 & 63;
        const int row = sb * 16 + (ln & 15), kl = ks8 * 32 + (ln >> 4) * 8;
        *(uint4*)(WhhF + dstb + (size_t)u4 * 8) = *(const uint4*)(Ls + row * 136 + kl);
    }
}

// h0 -> bf16 into hs slot 0; W_out -> bf16 padded to 48 rows; bsum raw
__global__ void prep_state(const float* __restrict__ h0, const float* __restrict__ W_out,
                           const float* __restrict__ b_ih, const float* __restrict__ b_hh,
                           unsigned short* __restrict__ hbuf, unsigned short* __restrict__ Woutp,
                           float* __restrict__ bsum) {
    const int b = blockIdx.x;
    const int t = threadIdx.x;
    if (b < 1024) {
        const size_t i = ((size_t)b * 256 + t) * 4;
        float4 hv = *(const float4*)(h0 + i);
        hbuf[i + 0] = f2bf(hv.x);
        hbuf[i + 1] = f2bf(hv.y);
        hbuf[i + 2] = f2bf(hv.z);
        hbuf[i + 3] = f2bf(hv.w);
    } else if (b < 1072) {
        const int o = b - 1024;                     // 0..47
        const int k = t * 4;
        float4 w = make_float4(0.f, 0.f, 0.f, 0.f);
        if (o < OUT_DIM) w = *(const float4*)(W_out + (size_t)o * E_DIM + k);
        const size_t dst = (size_t)o * E_DIM + k;
        Woutp[dst + 0] = f2bf(w.x);
        Woutp[dst + 1] = f2bf(w.y);
        Woutp[dst + 2] = f2bf(w.z);
        Woutp[dst + 3] = f2bf(w.w);
    } else {
        const int n = (b - 1072) * 256 + t;         // 0..4095
        bsum[n] = b_ih[n] + b_hh[n];
    }
}

// One fused LSTM step. Grid (32 bn2, 16 bm) = 512 blocks, 512 threads = 8 waves,
// 2 blocks/CU -> 16 waves/CU (launch_bounds 512,4 => vgpr<=128).
// Block: 64 batch rows x 128 perm N-rows (= e in [32*bn2,+32), all 4 gates).
// Wave (wm=wave>>2, wn=wave&3): 32m x 32n (mt=2 x nt=2), gates {2*(wn&1),+1}, eb_loc=wn>>1.
// W streamed via dbuf eighth-K LDS (2 x 32 KB, frag-linear); A global->reg 2-chunk ring.
// Epilogue: LDS gate-exchange (aliases W bufs), elementwise c/h on RAW C layout.
__global__ __launch_bounds__(512, 4) void lstm_step(
    const unsigned short* __restrict__ WF,   // fragment-order, per-bn2 slices of 256 KB
    const float* __restrict__ bsum,          // [4096] raw gate-major bias
    const unsigned short* __restrict__ Hin,  // [1024][1024] bf16
    float* __restrict__ C,                   // [1024][1024] f32 raw
    unsigned short* __restrict__ Hout)       // [1024][1024] bf16
{
    extern __shared__ __align__(16) unsigned short smem[];
    unsigned short* Wb[2] = { smem, smem + WSL_ELEMS };   // 2 x 32 KB

    const int tid  = threadIdx.x;
    const int wave = tid >> 6;
    const int lane = tid & 63;
    const int bn2 = blockIdx.x;
    const int bm  = blockIdx.y;
    const int wm = wave >> 2;          // 0..1  (m half)
    const int wn = wave & 3;           // 0..3  (n slot)
    const int j  = lane & 15;
    const int q  = lane >> 4;

    f32x4 acc[2][2];
#pragma unroll
    for (int a = 0; a < 2; ++a)
#pragma unroll
        for (int b = 0; b < 2; ++b) acc[a][b] = (f32x4){0.f, 0.f, 0.f, 0.f};

    // A row bases: m = bm*64 + wm*32 + mt*16 + j
    const unsigned short* arow0 = Hin + (size_t)(bm * 64 + wm * 32 + j) * E_DIM + q * 8;
    const unsigned short* arow1 = arow0 + (size_t)16 * E_DIM;
    const unsigned short* wsrc  = WF + (size_t)bn2 * 131072;

    // A ring: 2 chunks x 2 k-iters x 2 mt
    uint4 ra[2][2][2];
#pragma unroll
    for (int s = 0; s < 2; ++s) {
        ra[0][s][0] = *(const uint4*)(arow0 + s * 32);
        ra[0][s][1] = *(const uint4*)(arow1 + s * 32);
    }
    // stage W eighth 0 (linear copy, 32 KB)
    uint4 wreg[4];
#pragma unroll
    for (int i = 0; i < 4; ++i)
        wreg[i] = *(const uint4*)(wsrc + (i * 512 + tid) * 8);
#pragma unroll
    for (int i = 0; i < 4; ++i)
        *(uint4*)(Wb[0] + (i * 512 + tid) * 8) = wreg[i];
    __syncthreads();

    // wave's B base: elem off = ks8*4096 + (wn*2+nt)*512 + lane*8
    const int wboff = wn * 1024 + lane * 8;

#pragma unroll
    for (int E8 = 0; E8 < 8; ++E8) {
        const unsigned short* wb = Wb[E8 & 1] + wboff;
        if (E8 < 7) {       // issue next eighth's W loads early
#pragma unroll
            for (int i = 0; i < 4; ++i)
                wreg[i] = *(const uint4*)(wsrc + (size_t)(E8 + 1) * WSL_ELEMS + (i * 512 + tid) * 8);
        }
#pragma unroll
        for (int ch = 0; ch < 2; ++ch) {
            const int ci  = E8 * 2 + ch;
            const int cur = ci & 1;
            const int gi0 = ci * 2;
            if (gi0 + 2 < 32) {        // prefetch next chunk's A (block of 4 loads)
#pragma unroll
                for (int s = 0; s < 2; ++s) {
                    ra[1 - cur][s][0] = *(const uint4*)(arow0 + (gi0 + 2 + s) * 32);
                    ra[1 - cur][s][1] = *(const uint4*)(arow1 + (gi0 + 2 + s) * 32);
                }
            }
#pragma unroll
            for (int s = 0; s < 2; ++s) {
                const int ks8 = ch * 2 + s;
                bf16x8 av0 = __builtin_bit_cast(bf16x8, ra[cur][s][0]);
                bf16x8 av1 = __builtin_bit_cast(bf16x8, ra[cur][s][1]);
                bf16x8 bv0 = *(const bf16x8*)(wb + ks8 * 4096);
                bf16x8 bv1 = *(const bf16x8*)(wb + ks8 * 4096 + 512);
                acc[0][0] = __builtin_amdgcn_mfma_f32_16x16x32_bf16(av0, bv0, acc[0][0], 0, 0, 0);
                acc[0][1] = __builtin_amdgcn_mfma_f32_16x16x32_bf16(av0, bv1, acc[0][1], 0, 0, 0);
                acc[1][0] = __builtin_amdgcn_mfma_f32_16x16x32_bf16(av1, bv0, acc[1][0], 0, 0, 0);
                acc[1][1] = __builtin_amdgcn_mfma_f32_16x16x32_bf16(av1, bv1, acc[1][1], 0, 0, 0);
            }
        }
        if (E8 < 7) {
            unsigned short* wn_ = Wb[(E8 + 1) & 1];
#pragma unroll
            for (int i = 0; i < 4; ++i)
                *(uint4*)(wn_ + (i * 512 + tid) * 8) = wreg[i];
            __syncthreads();
        }
    }

    // ---- Epilogue: block-level gate exchange through LDS (aliases W buffers) ----
    __syncthreads();                       // all B-reads done; W bufs dead
    float* Gb = (float*)smem;              // [4 gates][64 m][32 e] f32 = 32 KB
    {
        const int gp = wn & 1, ebl = wn >> 1;
#pragma unroll
        for (int mt = 0; mt < 2; ++mt)
#pragma unroll
            for (int nt = 0; nt < 2; ++nt) {
                const int gate = 2 * gp + nt;
                const int el = ebl * 16 + j;
#pragma unroll
                for (int r = 0; r < 4; ++r) {
                    const int ml = wm * 32 + mt * 16 + q * 4 + r;
                    Gb[(gate * 64 + ml) * 32 + el] = acc[mt][nt][r];
                }
            }
    }
    __syncthreads();
    {
        const int ml = tid >> 3;                    // 0..63
        const int e4 = (tid & 7) * 4;               // 0..28
        const int mg = bm * 64 + ml;
        const int eg = bn2 * 32 + e4;
        float4 vi = *(const float4*)(Gb + (0 * 64 + ml) * 32 + e4);
        float4 vf = *(const float4*)(Gb + (1 * 64 + ml) * 32 + e4);
        float4 vg = *(const float4*)(Gb + (2 * 64 + ml) * 32 + e4);
        float4 vo = *(const float4*)(Gb + (3 * 64 + ml) * 32 + e4);
        float4 bi = *(const float4*)(bsum + 0 * E_DIM + eg);
        float4 bf = *(const float4*)(bsum + 1 * E_DIM + eg);
        float4 bg = *(const float4*)(bsum + 2 * E_DIM + eg);
        float4 bo = *(const float4*)(bsum + 3 * E_DIM + eg);
        const size_t cidx = (size_t)mg * E_DIM + eg;
        float4 cold = *(const float4*)(C + cidx);
        float cn[4]; unsigned short hb[4];
        const float iv_[4] = {vi.x + bi.x, vi.y + bi.y, vi.z + bi.z, vi.w + bi.w};
        const float fv_[4] = {vf.x + bf.x, vf.y + bf.y, vf.z + bf.z, vf.w + bf.w};
        const float gv_[4] = {vg.x + bg.x, vg.y + bg.y, vg.z + bg.z, vg.w + bg.w};
        const float ov_[4] = {vo.x + bo.x, vo.y + bo.y, vo.z + bo.z, vo.w + bo.w};
        const float co_[4] = {cold.x, cold.y, cold.z, cold.w};
#pragma unroll
        for (int i = 0; i < 4; ++i) {
            const float iv = sigmoid_(iv_[i]);
            const float fv = sigmoid_(fv_[i]);
            const float gv = tanh_(gv_[i]);
            const float ov = sigmoid_(ov_[i]);
            const float c2 = fv * co_[i] + iv * gv;
            cn[i] = c2;
            hb[i] = f2bf(ov * tanh_(c2));
        }
        *(float4*)(C + cidx) = make_float4(cn[0], cn[1], cn[2], cn[3]);
        *(uint2*)(Hout + cidx) = *(const uint2*)hb;   // 8B store (4 bf16)
    }
}

// Output projection: out[b,t,o] = hs[t+1][b][:] . Wo[o][:] + b_out[o]
__global__ __launch_bounds__(256) void proj_kernel(
    const unsigned short* __restrict__ Hs,   // [T][B][E] bf16 (slot 1 of hs)
    const unsigned short* __restrict__ Wo,   // [48][E] bf16 (rows >=34 zero)
    const float* __restrict__ b_out,         // [34]
    float* __restrict__ Out)                 // [B][T][34]
{
    __shared__ float red[4][32][OUT_PAD];    // 24 KB

    const int tid = threadIdx.x, wave = tid >> 6, lane = tid & 63;
    const int j = lane & 15, q = lane >> 4;
    const int t  = blockIdx.y;
    const int bb = blockIdx.x;
    const unsigned short* Hbase = Hs + ((size_t)t * B_DIM + (size_t)bb * 32) * E_DIM;
    const int k0 = wave * 256;

    f32x4 acc[2][3];
#pragma unroll
    for (int a = 0; a < 2; ++a)
#pragma unroll
        for (int b = 0; b < 3; ++b) acc[a][b] = (f32x4){0.f, 0.f, 0.f, 0.f};

#pragma unroll
    for (int kk = 0; kk < 256; kk += 32) {
        const int kc = k0 + kk + q * 8;
        bf16x8 av[2], bv[3];
#pragma unroll
        for (int mt = 0; mt < 2; ++mt)
            av[mt] = *(const bf16x8*)(Hbase + (size_t)(mt * 16 + j) * E_DIM + kc);
#pragma unroll
        for (int nt = 0; nt < 3; ++nt)
            bv[nt] = *(const bf16x8*)(Wo + (size_t)(nt * 16 + j) * E_DIM + kc);
#pragma unroll
        for (int mt = 0; mt < 2; ++mt)
#pragma unroll
            for (int nt = 0; nt < 3; ++nt)
                acc[mt][nt] = __builtin_amdgcn_mfma_f32_16x16x32_bf16(av[mt], bv[nt], acc[mt][nt], 0, 0, 0);
    }

#pragma unroll
    for (int mt = 0; mt < 2; ++mt)
#pragma unroll
        for (int nt = 0; nt < 3; ++nt)
#pragma unroll
            for (int r = 0; r < 4; ++r)
                red[wave][mt * 16 + q * 4 + r][nt * 16 + j] = acc[mt][nt][r];
    __syncthreads();

#pragma unroll
    for (int ii = 0; ii < 6; ++ii) {
        const int idx = tid * 6 + ii;            // 0..1535 = 32 rows x 48 outs
        const int row = idx / OUT_PAD, o = idx % OUT_PAD;
        if (o < OUT_DIM) {
            const float s = red[0][row][o] + red[1][row][o] + red[2][row][o] + red[3][row][o];
            Out[((size_t)(bb * 32 + row) * T_STEPS + t) * OUT_DIM + o] = s + b_out[o];
        }
    }
}

extern "C" void kernel_launch(void* const* d_in, const int* in_sizes, int n_in,
                              void* d_out, int out_size, void* d_ws, size_t ws_size,
                              hipStream_t stream) {
    (void)in_sizes; (void)n_in; (void)out_size; (void)ws_size;
    const float* h     = (const float*)d_in[0];
    const float* c     = (const float*)d_in[1];
    const float* W_ih  = (const float*)d_in[2];
    const float* W_hh  = (const float*)d_in[3];
    const float* b_ih  = (const float*)d_in[4];
    const float* b_hh  = (const float*)d_in[5];
    const float* W_out = (const float*)d_in[6];
    const float* b_out = (const float*)d_in[7];
    float* out = (float*)d_out;

    char* ws = (char*)d_ws;
    unsigned short* WsumF = (unsigned short*)(ws + 0);          //  8 MB fragment-order
    unsigned short* WhhF  = (unsigned short*)(ws + 8388608);    //  8 MB fragment-order
    float*          bsum  = (float*)(ws + 16777216);            // 16 KB
    unsigned short* Woutp = (unsigned short*)(ws + 16842752);   // 96 KB
    float*          cbuf  = (float*)(ws + 16941056);            //  4 MB raw f32
    unsigned short* hs    = (unsigned short*)(ws + 21135360);   // 22 MB: slot0=h0, slots1..10

    // host-side attribute set (not a stream op; safe under graph capture)
    hipFuncSetAttribute((const void*)lstm_step,
                        hipFuncAttributeMaxDynamicSharedMemorySize, DYN_LDS);

    prep_weights_frag<<<256, 512, 0, stream>>>(W_ih, W_hh, WsumF, WhhF);
    prep_state<<<1088, 256, 0, stream>>>(h, W_out, b_ih, b_hh, hs, Woutp, bsum);
    hipMemcpyAsync(cbuf, c, (size_t)B_DIM * E_DIM * sizeof(float),
                   hipMemcpyDeviceToDevice, stream);

    // step 0: x = 0 -> W_hh only; steps 1..9: x == h_prev -> fused W_ih + W_hh
    lstm_step<<<dim3(32, 16), 512, DYN_LDS, stream>>>(WhhF, bsum, hs, cbuf,
                                                      hs + (size_t)B_DIM * E_DIM);
    for (int t = 1; t < T_STEPS; ++t)
        lstm_step<<<dim3(32, 16), 512, DYN_LDS, stream>>>(WsumF, bsum,
                                                          hs + (size_t)t * B_DIM * E_DIM,
                                                          cbuf,
                                                          hs + (size_t)(t + 1) * B_DIM * E_DIM);

    proj_kernel<<<dim3(32, T_STEPS), 256, 0, stream>>>(hs + (size_t)B_DIM * E_DIM,
                                                       Woutp, b_out, out);
}

// Round 10
// 469.472 us; speedup vs baseline: 1.0010x; 1.0010x over previous
//
#include <hip/hip_runtime.h>
#include <cstdint>
#include <cstddef>

#define E_DIM   1024
#define B_DIM   1024
#define T_STEPS 10
#define OUT_DIM 34
#define OUT_PAD 48
#define EK      128                 // k-elements per eighth
#define WE_ELEMS (64 * EK)          // 8192 elems = 16 KB per eighth-slice buffer
#define GSTR    20                  // gate-exchange row stride (16 e + pad, float4-aligned)
#define DYN_LDS (2 * WE_ELEMS * 2)  // 32768 B

typedef __attribute__((ext_vector_type(4))) float  f32x4;
typedef __attribute__((ext_vector_type(8))) __bf16 bf16x8;

__device__ __forceinline__ unsigned short f2bf(float f) {
    unsigned int u = __float_as_uint(f);
    u = (u + 0x7FFFu + ((u >> 16) & 1u)) >> 16;   // round-to-nearest-even
    return (unsigned short)u;
}
__device__ __forceinline__ float sigmoid_(float x) { return 1.0f / (1.0f + __expf(-x)); }
__device__ __forceinline__ float tanh_(float x)    { return 2.0f / (1.0f + __expf(-2.0f * x)) - 1.0f; }

// Weights in MFMA-B-fragment order (PROVEN at 330 us in R6/R7, reused verbatim):
//   WF[bn(64)][E(8)][ks8(4)][gate(4)][lane(64)][8]
// frag elem: gate, e = bn*16 + (lane&15); k = E*128 + ks8*32 + (lane>>4)*8 + e8.
__global__ void prep_weights_frag(const float* __restrict__ W_ih, const float* __restrict__ W_hh,
                                  unsigned short* __restrict__ WsumF, unsigned short* __restrict__ WhhF) {
    const int bn = blockIdx.x >> 3, E = blockIdx.x & 7;
    const int nt = threadIdx.x >> 6, lane = threadIdx.x & 63;
    const int j = lane & 15, q = lane >> 4;
    const int srow = nt * E_DIM + bn * 16 + j;
    const float* wi = W_ih + (size_t)srow * E_DIM;
    const float* wh = W_hh + (size_t)srow * E_DIM;
    const size_t dstb = (size_t)bn * 65536 + (size_t)E * 8192 + nt * 512 + lane * 8;
#pragma unroll
    for (int ks8 = 0; ks8 < 4; ++ks8) {
        const int k = E * 128 + ks8 * 32 + q * 8;
        float4 i0 = *(const float4*)(wi + k);
        float4 i1 = *(const float4*)(wi + k + 4);
        float4 h0 = *(const float4*)(wh + k);
        float4 h1 = *(const float4*)(wh + k + 4);
        unsigned short s[8], hh[8];
        s[0] = f2bf(i0.x + h0.x); s[1] = f2bf(i0.y + h0.y);
        s[2] = f2bf(i0.z + h0.z); s[3] = f2bf(i0.w + h0.w);
        s[4] = f2bf(i1.x + h1.x); s[5] = f2bf(i1.y + h1.y);
        s[6] = f2bf(i1.z + h1.z); s[7] = f2bf(i1.w + h1.w);
        hh[0] = f2bf(h0.x); hh[1] = f2bf(h0.y); hh[2] = f2bf(h0.z); hh[3] = f2bf(h0.w);
        hh[4] = f2bf(h1.x); hh[5] = f2bf(h1.y); hh[6] = f2bf(h1.z); hh[7] = f2bf(h1.w);
        *(uint4*)(WsumF + dstb + ks8 * 2048) = *(const uint4*)s;
        *(uint4*)(WhhF  + dstb + ks8 * 2048) = *(const uint4*)hh;
    }
}

// h0 -> bf16 into hs slot 0; W_out -> bf16 padded to 48 rows; bias permuted
// bperm[bn*64 + g*16 + j] = b_ih[g*1024 + bn*16 + j] + b_hh[same]  (R6 verbatim)
__global__ void prep_state(const float* __restrict__ h0, const float* __restrict__ W_out,
                           const float* __restrict__ b_ih, const float* __restrict__ b_hh,
                           unsigned short* __restrict__ hbuf, unsigned short* __restrict__ Woutp,
                           float* __restrict__ bperm) {
    const int b = blockIdx.x;
    const int t = threadIdx.x;
    if (b < 1024) {
        const size_t i = ((size_t)b * 256 + t) * 4;
        float4 hv = *(const float4*)(h0 + i);
        hbuf[i + 0] = f2bf(hv.x);
        hbuf[i + 1] = f2bf(hv.y);
        hbuf[i + 2] = f2bf(hv.z);
        hbuf[i + 3] = f2bf(hv.w);
    } else if (b < 1072) {
        const int o = b - 1024;                     // 0..47
        const int k = t * 4;
        float4 w = make_float4(0.f, 0.f, 0.f, 0.f);
        if (o < OUT_DIM) w = *(const float4*)(W_out + (size_t)o * E_DIM + k);
        const size_t dst = (size_t)o * E_DIM + k;
        Woutp[dst + 0] = f2bf(w.x);
        Woutp[dst + 1] = f2bf(w.y);
        Woutp[dst + 2] = f2bf(w.z);
        Woutp[dst + 3] = f2bf(w.w);
    } else {
        const int n = (b - 1072) * 256 + t;         // 0..4095 permuted index
        const int g = (n >> 4) & 3;
        const int e = ((n >> 6) << 4) | (n & 15);
        const int srow = g * E_DIM + e;
        bperm[n] = b_ih[srow] + b_hh[srow];
    }
}

// One fused LSTM step. Grid (64 bn, 16 bm) = 1024 blocks, 256 threads = 4 waves.
// 4 blocks/CU x 4 waves = 16 waves/CU (launch_bounds(256,4) => vgpr<=128; LDS 32KB).
// Block: 64 batch rows x 64 perm N-rows (e in [16*bn,+16), all 4 gates).
// Wave (wm=wave>>1, wn2=wave&1): 32m x 32n (mt=2, nt=2 -> gates {2*wn2, 2*wn2+1}).
// K-loop: R6's proven eighth-K ping-pong LDS W + dual-bank block-issued A.
// Epilogue: LDS gate-exchange (aliases W bufs), elementwise c/h on RAW C layout.
__global__ __launch_bounds__(256, 4) void lstm_step(
    const unsigned short* __restrict__ WF,   // [64][8][4][4][64][8] bf16 fragment-order
    const float* __restrict__ bp,            // [4096] permuted bias
    const unsigned short* __restrict__ Hin,  // [1024][1024] bf16
    float* __restrict__ C,                   // [1024][1024] f32 raw
    unsigned short* __restrict__ Hout)       // [1024][1024] bf16
{
    extern __shared__ __align__(16) unsigned short smem[];
    unsigned short* Wb[2] = { smem, smem + WE_ELEMS };   // 2 x 16 KB

    const int tid  = threadIdx.x;
    const int wave = tid >> 6;
    const int lane = tid & 63;
    const int bn = blockIdx.x;
    const int bm = blockIdx.y;
    const int wm  = wave >> 1;         // m half (0..1)
    const int wn2 = wave & 1;          // gate pair (0..1)
    const int j  = lane & 15;
    const int q  = lane >> 4;

    f32x4 acc[2][2];
#pragma unroll
    for (int a = 0; a < 2; ++a)
#pragma unroll
        for (int b = 0; b < 2; ++b) acc[a][b] = (f32x4){0.f, 0.f, 0.f, 0.f};

    // A row bases: m = bm*64 + wm*32 + mt*16 + j
    const unsigned short* arow0 = Hin + (size_t)(bm * 64 + wm * 32 + j) * E_DIM + q * 8;
    const unsigned short* arow1 = arow0 + (size_t)16 * E_DIM;
    const unsigned short* wsrc  = WF + (size_t)bn * 65536;   // this bn's 128 KB slice

    // dual-bank A registers: bank [E8&1] holds eighth E8's 4 ks x 2 mt (R6 pattern)
    uint4 ra[2][4][2];
#pragma unroll
    for (int s = 0; s < 4; ++s) {
        ra[0][s][0] = *(const uint4*)(arow0 + s * 32);
        ra[0][s][1] = *(const uint4*)(arow1 + s * 32);
    }
    // stage W eighth 0 (linear copy, 16 KB)
    uint4 wreg[4];
#pragma unroll
    for (int i = 0; i < 4; ++i)
        wreg[i] = *(const uint4*)(wsrc + (i * 256 + tid) * 8);
#pragma unroll
    for (int i = 0; i < 4; ++i)
        *(uint4*)(Wb[0] + (i * 256 + tid) * 8) = wreg[i];
    __syncthreads();

    // wave's B base within eighth buffer: (ks8*4 + wn2*2 + nt)*512 + lane*8
    const int wboff = wn2 * 1024 + lane * 8;

#pragma unroll
    for (int E8 = 0; E8 < 8; ++E8) {
        const int cur = E8 & 1;
        const unsigned short* wb = Wb[cur] + wboff;
        if (E8 < 7) {       // block-issue ALL next-eighth loads before the burst
#pragma unroll
            for (int s = 0; s < 4; ++s) {
                ra[1 - cur][s][0] = *(const uint4*)(arow0 + (E8 + 1) * EK + s * 32);
                ra[1 - cur][s][1] = *(const uint4*)(arow1 + (E8 + 1) * EK + s * 32);
            }
#pragma unroll
            for (int i = 0; i < 4; ++i)
                wreg[i] = *(const uint4*)(wsrc + (size_t)(E8 + 1) * WE_ELEMS + (i * 256 + tid) * 8);
        }
#pragma unroll
        for (int ks8 = 0; ks8 < 4; ++ks8) {
            bf16x8 av0 = __builtin_bit_cast(bf16x8, ra[cur][ks8][0]);
            bf16x8 av1 = __builtin_bit_cast(bf16x8, ra[cur][ks8][1]);
            bf16x8 bv0 = *(const bf16x8*)(wb + ks8 * 2048);
            bf16x8 bv1 = *(const bf16x8*)(wb + ks8 * 2048 + 512);
            acc[0][0] = __builtin_amdgcn_mfma_f32_16x16x32_bf16(av0, bv0, acc[0][0], 0, 0, 0);
            acc[0][1] = __builtin_amdgcn_mfma_f32_16x16x32_bf16(av0, bv1, acc[0][1], 0, 0, 0);
            acc[1][0] = __builtin_amdgcn_mfma_f32_16x16x32_bf16(av1, bv0, acc[1][0], 0, 0, 0);
            acc[1][1] = __builtin_amdgcn_mfma_f32_16x16x32_bf16(av1, bv1, acc[1][1], 0, 0, 0);
        }
        if (E8 < 7) {
            unsigned short* wn_ = Wb[1 - cur];
#pragma unroll
            for (int i = 0; i < 4; ++i)
                *(uint4*)(wn_ + (i * 256 + tid) * 8) = wreg[i];
            __syncthreads();
        }
    }

    // ---- Epilogue: gate exchange through LDS (aliases dead W buffers) ----
    __syncthreads();                       // all waves' B-reads done before overwrite
    float* Gb = (float*)smem;              // [4 gates][64 m][GSTR] f32 = 20 KB
    {
#pragma unroll
        for (int mt = 0; mt < 2; ++mt)
#pragma unroll
            for (int nt = 0; nt < 2; ++nt) {
                const int gate = wn2 * 2 + nt;
#pragma unroll
                for (int r = 0; r < 4; ++r) {
                    const int ml = wm * 32 + mt * 16 + q * 4 + r;
                    Gb[(gate * 64 + ml) * GSTR + j] = acc[mt][nt][r];
                }
            }
    }
    __syncthreads();
    {
        const int ml = tid >> 2;                    // 0..63
        const int e4 = (tid & 3) * 4;               // 0,4,8,12
        float4 vi = *(const float4*)(Gb + (0 * 64 + ml) * GSTR + e4);
        float4 vf = *(const float4*)(Gb + (1 * 64 + ml) * GSTR + e4);
        float4 vg = *(const float4*)(Gb + (2 * 64 + ml) * GSTR + e4);
        float4 vo = *(const float4*)(Gb + (3 * 64 + ml) * GSTR + e4);
        float4 bi = *(const float4*)(bp + bn * 64 +  0 + e4);
        float4 bf = *(const float4*)(bp + bn * 64 + 16 + e4);
        float4 bg = *(const float4*)(bp + bn * 64 + 32 + e4);
        float4 bo = *(const float4*)(bp + bn * 64 + 48 + e4);
        const size_t cidx = (size_t)(bm * 64 + ml) * E_DIM + bn * 16 + e4;
        float4 cold = *(const float4*)(C + cidx);
        float cn[4]; unsigned short hb[4];
        const float iv_[4] = {vi.x + bi.x, vi.y + bi.y, vi.z + bi.z, vi.w + bi.w};
        const float fv_[4] = {vf.x + bf.x, vf.y + bf.y, vf.z + bf.z, vf.w + bf.w};
        const float gv_[4] = {vg.x + bg.x, vg.y + bg.y, vg.z + bg.z, vg.w + bg.w};
        const float ov_[4] = {vo.x + bo.x, vo.y + bo.y, vo.z + bo.z, vo.w + bo.w};
        const float co_[4] = {cold.x, cold.y, cold.z, cold.w};
#pragma unroll
        for (int i = 0; i < 4; ++i) {
            const float iv = sigmoid_(iv_[i]);
            const float fv = sigmoid_(fv_[i]);
            const float gv = tanh_(gv_[i]);
            const float ov = sigmoid_(ov_[i]);
            const float c2 = fv * co_[i] + iv * gv;
            cn[i] = c2;
            hb[i] = f2bf(ov * tanh_(c2));
        }
        *(float4*)(C + cidx) = make_float4(cn[0], cn[1], cn[2], cn[3]);
        *(uint2*)(Hout + cidx) = *(const uint2*)hb;   // 8B store (4 bf16)
    }
}

// Output projection: out[b,t,o] = hs[t+1][b][:] . Wo[o][:] + b_out[o]  (R9 verbatim)
__global__ __launch_bounds__(256) void proj_kernel(
    const unsigned short* __restrict__ Hs,   // [T][B][E] bf16 (slot 1 of hs)
    const unsigned short* __restrict__ Wo,   // [48][E] bf16 (rows >=34 zero)
    const float* __restrict__ b_out,         // [34]
    float* __restrict__ Out)                 // [B][T][34]
{
    __shared__ float red[4][32][OUT_PAD];    // 24 KB

    const int tid = threadIdx.x, wave = tid >> 6, lane = tid & 63;
    const int j = lane & 15, q = lane >> 4;
    const int t  = blockIdx.y;
    const int bb = blockIdx.x;
    const unsigned short* Hbase = Hs + ((size_t)t * B_DIM + (size_t)bb * 32) * E_DIM;
    const int k0 = wave * 256;

    f32x4 acc[2][3];
#pragma unroll
    for (int a = 0; a < 2; ++a)
#pragma unroll
        for (int b = 0; b < 3; ++b) acc[a][b] = (f32x4){0.f, 0.f, 0.f, 0.f};

#pragma unroll
    for (int kk = 0; kk < 256; kk += 32) {
        const int kc = k0 + kk + q * 8;
        bf16x8 av[2], bv[3];
#pragma unroll
        for (int mt = 0; mt < 2; ++mt)
            av[mt] = *(const bf16x8*)(Hbase + (size_t)(mt * 16 + j) * E_DIM + kc);
#pragma unroll
        for (int nt = 0; nt < 3; ++nt)
            bv[nt] = *(const bf16x8*)(Wo + (size_t)(nt * 16 + j) * E_DIM + kc);
#pragma unroll
        for (int mt = 0; mt < 2; ++mt)
#pragma unroll
            for (int nt = 0; nt < 3; ++nt)
                acc[mt][nt] = __builtin_amdgcn_mfma_f32_16x16x32_bf16(av[mt], bv[nt], acc[mt][nt], 0, 0, 0);
    }

#pragma unroll
    for (int mt = 0; mt < 2; ++mt)
#pragma unroll
        for (int nt = 0; nt < 3; ++nt)
#pragma unroll
            for (int r = 0; r < 4; ++r)
                red[wave][mt * 16 + q * 4 + r][nt * 16 + j] = acc[mt][nt][r];
    __syncthreads();

#pragma unroll
    for (int ii = 0; ii < 6; ++ii) {
        const int idx = tid * 6 + ii;            // 0..1535 = 32 rows x 48 outs
        const int row = idx / OUT_PAD, o = idx % OUT_PAD;
        if (o < OUT_DIM) {
            const float s = red[0][row][o] + red[1][row][o] + red[2][row][o] + red[3][row][o];
            Out[((size_t)(bb * 32 + row) * T_STEPS + t) * OUT_DIM + o] = s + b_out[o];
        }
    }
}

extern "C" void kernel_launch(void* const* d_in, const int* in_sizes, int n_in,
                              void* d_out, int out_size, void* d_ws, size_t ws_size,
                              hipStream_t stream) {
    (void)in_sizes; (void)n_in; (void)out_size; (void)ws_size;
    const float* h     = (const float*)d_in[0];
    const float* c     = (const float*)d_in[1];
    const float* W_ih  = (const float*)d_in[2];
    const float* W_hh  = (const float*)d_in[3];
    const float* b_ih  = (const float*)d_in[4];
    const float* b_hh  = (const float*)d_in[5];
    const float* W_out = (const float*)d_in[6];
    const float* b_out = (const float*)d_in[7];
    float* out = (float*)d_out;

    char* ws = (char*)d_ws;
    unsigned short* WsumF = (unsigned short*)(ws + 0);          //  8 MB fragment-order
    unsigned short* WhhF  = (unsigned short*)(ws + 8388608);    //  8 MB fragment-order
    float*          bperm = (float*)(ws + 16777216);            // 16 KB
    unsigned short* Woutp = (unsigned short*)(ws + 16842752);   // 96 KB
    float*          cbuf  = (float*)(ws + 16941056);            //  4 MB raw f32
    unsigned short* hs    = (unsigned short*)(ws + 21135360);   // 22 MB: slot0=h0, slots1..10

    // host-side attribute set (not a stream op; safe under graph capture)
    hipFuncSetAttribute((const void*)lstm_step,
                        hipFuncAttributeMaxDynamicSharedMemorySize, DYN_LDS);

    prep_weights_frag<<<512, 256, 0, stream>>>(W_ih, W_hh, WsumF, WhhF);
    prep_state<<<1088, 256, 0, stream>>>(h, W_out, b_ih, b_hh, hs, Woutp, bperm);
    hipMemcpyAsync(cbuf, c, (size_t)B_DIM * E_DIM * sizeof(float),
                   hipMemcpyDeviceToDevice, stream);

    // step 0: x = 0 -> W_hh only; steps 1..9: x == h_prev -> fused W_ih + W_hh
    lstm_step<<<dim3(64, 16), 256, DYN_LDS, stream>>>(WhhF, bperm, hs, cbuf,
                                                      hs + (size_t)B_DIM * E_DIM);
    for (int t = 1; t < T_STEPS; ++t)
        lstm_step<<<dim3(64, 16), 256, DYN_LDS, stream>>>(WsumF, bperm,
                                                          hs + (size_t)t * B_DIM * E_DIM,
                                                          cbuf,
                                                          hs + (size_t)(t + 1) * B_DIM * E_DIM);

    proj_kernel<<<dim3(32, T_STEPS), 256, 0, stream>>>(hs + (size_t)B_DIM * E_DIM,
                                                       Woutp, b_out, out);
}

// Round 11
// 363.501 us; speedup vs baseline: 1.2928x; 1.2915x over previous
//
#include <hip/hip_runtime.h>
#include <cstdint>
#include <cstddef>

#define E_DIM   1024
#define B_DIM   1024
#define T_STEPS 10
#define OUT_DIM 34
#define OUT_PAD 48
#define EK      128                  // k-elements per eighth
#define WE_ELEMS (128 * EK)          // 16384 elems = 32 KB per eighth buffer
#define SLICE_ELEMS (8 * WE_ELEMS)   // 131072 elems = 256 KB per bn slice
#define HSTR    48                   // h-transpose row stride (32 e + pad, 16B-aligned)
#define DYN_LDS (2 * WE_ELEMS * 2)   // 65536 B

typedef __attribute__((ext_vector_type(4))) float  f32x4;
typedef __attribute__((ext_vector_type(8))) __bf16 bf16x8;

__device__ __forceinline__ unsigned short f2bf(float f) {
    unsigned int u = __float_as_uint(f);
    u = (u + 0x7FFFu + ((u >> 16) & 1u)) >> 16;   // round-to-nearest-even
    return (unsigned short)u;
}
__device__ __forceinline__ float sigmoid_(float x) { return 1.0f / (1.0f + __expf(-x)); }
__device__ __forceinline__ float tanh_(float x)    { return 2.0f / (1.0f + __expf(-2.0f * x)) - 1.0f; }

// Weights in MFMA-B-fragment order for the 128x128 block tile:
//   WF[bn(32)][E8(8)][ks8(4)][sub(8)][lane(64)][8]
// sub = wn*4 + gate; decode: gate = sub&3, e = bn*32 + (sub>>2)*16 + (lane&15);
// k = E8*128 + ks8*32 + (lane>>4)*8 + i.  Staging in lstm_step is a pure linear
// copy; B-read = base + lane*16B with static immediate offsets (conflict-free).
__global__ __launch_bounds__(512) void prep_weights_frag(
    const float* __restrict__ W_ih, const float* __restrict__ W_hh,
    unsigned short* __restrict__ WsumF, unsigned short* __restrict__ WhhF) {
    const int bn = blockIdx.x >> 3, E8 = blockIdx.x & 7;
    const int sub = threadIdx.x >> 6, lane = threadIdx.x & 63;
    const int j = lane & 15, q = lane >> 4;
    const int g = sub & 3;
    const int e = bn * 32 + ((sub >> 2) << 4) + j;
    const float* wi = W_ih + ((size_t)g * E_DIM + e) * E_DIM;
    const float* wh = W_hh + ((size_t)g * E_DIM + e) * E_DIM;
    const size_t dstb = (size_t)bn * SLICE_ELEMS + (size_t)E8 * WE_ELEMS + sub * 512 + lane * 8;
#pragma unroll
    for (int ks8 = 0; ks8 < 4; ++ks8) {
        const int k = E8 * 128 + ks8 * 32 + q * 8;
        float4 i0 = *(const float4*)(wi + k);
        float4 i1 = *(const float4*)(wi + k + 4);
        float4 h0 = *(const float4*)(wh + k);
        float4 h1 = *(const float4*)(wh + k + 4);
        unsigned short s[8], hh[8];
        s[0] = f2bf(i0.x + h0.x); s[1] = f2bf(i0.y + h0.y);
        s[2] = f2bf(i0.z + h0.z); s[3] = f2bf(i0.w + h0.w);
        s[4] = f2bf(i1.x + h1.x); s[5] = f2bf(i1.y + h1.y);
        s[6] = f2bf(i1.z + h1.z); s[7] = f2bf(i1.w + h1.w);
        hh[0] = f2bf(h0.x); hh[1] = f2bf(h0.y); hh[2] = f2bf(h0.z); hh[3] = f2bf(h0.w);
        hh[4] = f2bf(h1.x); hh[5] = f2bf(h1.y); hh[6] = f2bf(h1.z); hh[7] = f2bf(h1.w);
        *(uint4*)(WsumF + dstb + ks8 * 4096) = *(const uint4*)s;
        *(uint4*)(WhhF  + dstb + ks8 * 4096) = *(const uint4*)hh;
    }
}

// h0 -> bf16 into hs slot 0; W_out -> bf16 padded to 48 rows; bias permuted:
// bperm[n], n = bn*128 + sub*16 + j, sub = wn*4+g -> srow = g*1024 + bn*32 + (sub>>2)*16 + j
__global__ void prep_state(const float* __restrict__ h0, const float* __restrict__ W_out,
                           const float* __restrict__ b_ih, const float* __restrict__ b_hh,
                           unsigned short* __restrict__ hbuf, unsigned short* __restrict__ Woutp,
                           float* __restrict__ bperm) {
    const int b = blockIdx.x;
    const int t = threadIdx.x;
    if (b < 1024) {
        const size_t i = ((size_t)b * 256 + t) * 4;
        float4 hv = *(const float4*)(h0 + i);
        hbuf[i + 0] = f2bf(hv.x);
        hbuf[i + 1] = f2bf(hv.y);
        hbuf[i + 2] = f2bf(hv.z);
        hbuf[i + 3] = f2bf(hv.w);
    } else if (b < 1072) {
        const int o = b - 1024;                     // 0..47
        const int k = t * 4;
        float4 w = make_float4(0.f, 0.f, 0.f, 0.f);
        if (o < OUT_DIM) w = *(const float4*)(W_out + (size_t)o * E_DIM + k);
        const size_t dst = (size_t)o * E_DIM + k;
        Woutp[dst + 0] = f2bf(w.x);
        Woutp[dst + 1] = f2bf(w.y);
        Woutp[dst + 2] = f2bf(w.z);
        Woutp[dst + 3] = f2bf(w.w);
    } else {
        const int n = (b - 1072) * 256 + t;         // 0..4095 permuted index
        const int bn = n >> 7, sub = (n >> 4) & 7, j = n & 15;
        const int g = sub & 3;
        const int e = bn * 32 + ((sub >> 2) << 4) + j;
        bperm[n] = b_ih[g * E_DIM + e] + b_hh[g * E_DIM + e];
    }
}

// Permute initial c into MFMA-accumulator-flat layout used by lstm_step:
// idx = (((bn*8+bm)*8 + wave)*64 + lane)*8 + mt*4 + r
// m = bm*128 + wm*32 + mt*16 + q*4 + r (wm=wave>>1), e = bn*32 + wn*16 + j (wn=wave&1).
__global__ void prep_c(const float* __restrict__ c0, float* __restrict__ C) {
    const int m = blockIdx.x;
    const int e0 = threadIdx.x * 4;
    float4 v = *(const float4*)(c0 + (size_t)m * E_DIM + e0);
    const int bm = m >> 7, wm = (m >> 5) & 3, mt = (m >> 4) & 1, q = (m >> 2) & 3, r = m & 3;
    const float vv[4] = {v.x, v.y, v.z, v.w};
#pragma unroll
    for (int ii = 0; ii < 4; ++ii) {
        const int e = e0 + ii;
        const int bn = e >> 5, wn = (e >> 4) & 1, j = e & 15;
        const int wave = wm * 2 + wn;
        const int lane = q * 16 + j;
        C[(((size_t)(bn * 8 + bm) * 8 + wave) * 64 + lane) * 8 + mt * 4 + r] = vv[ii];
    }
}

// One fused LSTM step, traffic-optimal 128x128 tile.
// Grid (32 bn, 8 bm) = 256 blocks (1/CU), 512 threads = 8 waves (8 waves/CU).
// Redundant traffic/step: A 32bn x 2MB = 64 MB + W 8bm x 8MB = 64 MB = 128 MB
// (vs 192 MB in the 330-us config, 256 MB in the 470-us configs).
// Wave (wm=wave>>1, wn=wave&1): 32m x 64n; nt == gate -> lane-local LSTM epilogue.
// K-loop: eighth-K ping-pong LDS W (2 x 32 KB) + dual-bank block-issued A regs.
__global__ __launch_bounds__(512, 2) void lstm_step(
    const unsigned short* __restrict__ WF,   // [32][8][4][8][64][8] bf16 fragment-order
    const float* __restrict__ bp,            // [4096] permuted bias
    const unsigned short* __restrict__ Hin,  // [1024][1024] bf16
    float* __restrict__ C,                   // [B*E] f32 in MFMA-flat layout
    unsigned short* __restrict__ Hout)       // [1024][1024] bf16
{
    extern __shared__ __align__(16) unsigned short smem[];
    unsigned short* Wb[2] = { smem, smem + WE_ELEMS };   // 2 x 32 KB

    const int tid  = threadIdx.x;
    const int wave = tid >> 6;
    const int lane = tid & 63;
    const int bn = blockIdx.x;
    const int bm = blockIdx.y;
    const int wm = wave >> 1;          // 0..3 (m quarter)
    const int wn = wave & 1;           // 0..1 (e half)
    const int j  = lane & 15;
    const int q  = lane >> 4;

    f32x4 acc[2][4];
#pragma unroll
    for (int a = 0; a < 2; ++a)
#pragma unroll
        for (int b = 0; b < 4; ++b) acc[a][b] = (f32x4){0.f, 0.f, 0.f, 0.f};

    // hoisted far-from-use loads: biases + old cell state
    const int nb = bn * 128 + wn * 64 + j;
    const float bi = bp[nb +  0];
    const float bf = bp[nb + 16];
    const float bg = bp[nb + 32];
    const float bo = bp[nb + 48];
    const size_t cbase = (((size_t)(bn * 8 + bm) * 8 + wave) * 64 + lane) * 8;
    float4 cold0 = *(const float4*)(C + cbase);
    float4 cold1 = *(const float4*)(C + cbase + 4);

    // A row bases: m = bm*128 + wm*32 + mt*16 + j
    const unsigned short* arow0 = Hin + (size_t)(bm * 128 + wm * 32 + j) * E_DIM + q * 8;
    const unsigned short* arow1 = arow0 + (size_t)16 * E_DIM;
    const unsigned short* wsrc  = WF + (size_t)bn * SLICE_ELEMS;   // this bn's 256 KB slice

    // dual-bank A registers: bank [E8&1] holds eighth E8's 4 ks8 x 2 mt
    uint4 ra[2][4][2];
#pragma unroll
    for (int s = 0; s < 4; ++s) {
        ra[0][s][0] = *(const uint4*)(arow0 + s * 32);
        ra[0][s][1] = *(const uint4*)(arow1 + s * 32);
    }
    // stage W eighth 0 (pure linear copy, 32 KB: 512 thr x 4 x 16 B)
    uint4 wreg[4];
#pragma unroll
    for (int i = 0; i < 4; ++i)
        wreg[i] = *(const uint4*)(wsrc + (i * 512 + tid) * 8);
#pragma unroll
    for (int i = 0; i < 4; ++i)
        *(uint4*)(Wb[0] + (i * 512 + tid) * 8) = wreg[i];
    __syncthreads();

    // wave's B base: elem off = ks8*4096 + wn*2048 + nt*512 + lane*8
    const int wboff = wn * 2048 + lane * 8;

#pragma unroll
    for (int E8 = 0; E8 < 8; ++E8) {
        const int cur = E8 & 1;
        const unsigned short* wb = Wb[cur] + wboff;
        if (E8 < 7) {       // block-issue ALL next-eighth loads before the burst
#pragma unroll
            for (int s = 0; s < 4; ++s) {
                ra[1 - cur][s][0] = *(const uint4*)(arow0 + (E8 + 1) * EK + s * 32);
                ra[1 - cur][s][1] = *(const uint4*)(arow1 + (E8 + 1) * EK + s * 32);
            }
#pragma unroll
            for (int i = 0; i < 4; ++i)
                wreg[i] = *(const uint4*)(wsrc + (size_t)(E8 + 1) * WE_ELEMS + (i * 512 + tid) * 8);
        }
#pragma unroll
        for (int ks8 = 0; ks8 < 4; ++ks8) {
            bf16x8 av0 = __builtin_bit_cast(bf16x8, ra[cur][ks8][0]);
            bf16x8 av1 = __builtin_bit_cast(bf16x8, ra[cur][ks8][1]);
            bf16x8 bv[4];
#pragma unroll
            for (int nt = 0; nt < 4; ++nt)
                bv[nt] = *(const bf16x8*)(wb + ks8 * 4096 + nt * 512);   // imm offsets
#pragma unroll
            for (int nt = 0; nt < 4; ++nt) {
                acc[0][nt] = __builtin_amdgcn_mfma_f32_16x16x32_bf16(av0, bv[nt], acc[0][nt], 0, 0, 0);
                acc[1][nt] = __builtin_amdgcn_mfma_f32_16x16x32_bf16(av1, bv[nt], acc[1][nt], 0, 0, 0);
            }
        }
        if (E8 < 7) {
            unsigned short* wn_ = Wb[1 - cur];
#pragma unroll
            for (int i = 0; i < 4; ++i)
                *(uint4*)(wn_ + (i * 512 + tid) * 8) = wreg[i];
            __syncthreads();
        }
    }

    // ---- Epilogue: nt == gate (i,f,g,o); lane-local LSTM update ----
    __syncthreads();                       // all MFMAs done; W buffers dead
    unsigned short* Ht = smem;             // [128 m][HSTR] bf16 = 12 KB (aliases Wb[0])
    float4 cnew[2];
    const float coldv[2][4] = {{cold0.x, cold0.y, cold0.z, cold0.w},
                               {cold1.x, cold1.y, cold1.z, cold1.w}};
#pragma unroll
    for (int mt = 0; mt < 2; ++mt) {
#pragma unroll
        for (int r = 0; r < 4; ++r) {
            const float iv = sigmoid_(acc[mt][0][r] + bi);
            const float fv = sigmoid_(acc[mt][1][r] + bf);
            const float gv = tanh_(acc[mt][2][r] + bg);
            const float ov = sigmoid_(acc[mt][3][r] + bo);
            const float cn = fv * coldv[mt][r] + iv * gv;
            cnew[mt][r] = cn;
            const int rowl = wm * 32 + mt * 16 + q * 4 + r;   // 0..127
            Ht[rowl * HSTR + wn * 16 + j] = f2bf(ov * tanh_(cn));
        }
    }
    *(float4*)(C + cbase)     = cnew[0];
    *(float4*)(C + cbase + 4) = cnew[1];
    __syncthreads();

    // coalesced h store: 4 threads per row, 16 B each (64 B/row contiguous)
    {
        const int row = tid >> 2, part = (tid & 3) * 8;
        uint4 v = *(const uint4*)(Ht + row * HSTR + part);
        *(uint4*)(Hout + (size_t)(bm * 128 + row) * E_DIM + bn * 32 + part) = v;
    }
}

// Output projection: out[b,t,o] = hs[t+1][b][:] . Wo[o][:] + b_out[o]
__global__ __launch_bounds__(256) void proj_kernel(
    const unsigned short* __restrict__ Hs,   // [T][B][E] bf16 (slot 1 of hs)
    const unsigned short* __restrict__ Wo,   // [48][E] bf16 (rows >=34 zero)
    const float* __restrict__ b_out,         // [34]
    float* __restrict__ Out)                 // [B][T][34]
{
    __shared__ float red[4][32][OUT_PAD];    // 24 KB

    const int tid = threadIdx.x, wave = tid >> 6, lane = tid & 63;
    const int j = lane & 15, q = lane >> 4;
    const int t  = blockIdx.y;
    const int bb = blockIdx.x;
    const unsigned short* Hbase = Hs + ((size_t)t * B_DIM + (size_t)bb * 32) * E_DIM;
    const int k0 = wave * 256;

    f32x4 acc[2][3];
#pragma unroll
    for (int a = 0; a < 2; ++a)
#pragma unroll
        for (int b = 0; b < 3; ++b) acc[a][b] = (f32x4){0.f, 0.f, 0.f, 0.f};

#pragma unroll
    for (int kk = 0; kk < 256; kk += 32) {
        const int kc = k0 + kk + q * 8;
        bf16x8 av[2], bv[3];
#pragma unroll
        for (int mt = 0; mt < 2; ++mt)
            av[mt] = *(const bf16x8*)(Hbase + (size_t)(mt * 16 + j) * E_DIM + kc);
#pragma unroll
        for (int nt = 0; nt < 3; ++nt)
            bv[nt] = *(const bf16x8*)(Wo + (size_t)(nt * 16 + j) * E_DIM + kc);
#pragma unroll
        for (int mt = 0; mt < 2; ++mt)
#pragma unroll
            for (int nt = 0; nt < 3; ++nt)
                acc[mt][nt] = __builtin_amdgcn_mfma_f32_16x16x32_bf16(av[mt], bv[nt], acc[mt][nt], 0, 0, 0);
    }

#pragma unroll
    for (int mt = 0; mt < 2; ++mt)
#pragma unroll
        for (int nt = 0; nt < 3; ++nt)
#pragma unroll
            for (int r = 0; r < 4; ++r)
                red[wave][mt * 16 + q * 4 + r][nt * 16 + j] = acc[mt][nt][r];
    __syncthreads();

#pragma unroll
    for (int ii = 0; ii < 6; ++ii) {
        const int idx = tid * 6 + ii;            // 0..1535 = 32 rows x 48 outs
        const int row = idx / OUT_PAD, o = idx % OUT_PAD;
        if (o < OUT_DIM) {
            const float s = red[0][row][o] + red[1][row][o] + red[2][row][o] + red[3][row][o];
            Out[((size_t)(bb * 32 + row) * T_STEPS + t) * OUT_DIM + o] = s + b_out[o];
        }
    }
}

extern "C" void kernel_launch(void* const* d_in, const int* in_sizes, int n_in,
                              void* d_out, int out_size, void* d_ws, size_t ws_size,
                              hipStream_t stream) {
    (void)in_sizes; (void)n_in; (void)out_size; (void)ws_size;
    const float* h     = (const float*)d_in[0];
    const float* c     = (const float*)d_in[1];
    const float* W_ih  = (const float*)d_in[2];
    const float* W_hh  = (const float*)d_in[3];
    const float* b_ih  = (const float*)d_in[4];
    const float* b_hh  = (const float*)d_in[5];
    const float* W_out = (const float*)d_in[6];
    const float* b_out = (const float*)d_in[7];
    float* out = (float*)d_out;

    char* ws = (char*)d_ws;
    unsigned short* WsumF = (unsigned short*)(ws + 0);          //  8 MB fragment-order
    unsigned short* WhhF  = (unsigned short*)(ws + 8388608);    //  8 MB fragment-order
    float*          bperm = (float*)(ws + 16777216);            // 16 KB
    unsigned short* Woutp = (unsigned short*)(ws + 16842752);   // 96 KB
    float*          cbuf  = (float*)(ws + 16941056);            //  4 MB (MFMA-flat)
    unsigned short* hs    = (unsigned short*)(ws + 21135360);   // 22 MB: slot0=h0, slots1..10

    // host-side attribute set (not a stream op; safe under graph capture)
    hipFuncSetAttribute((const void*)lstm_step,
                        hipFuncAttributeMaxDynamicSharedMemorySize, DYN_LDS);

    prep_weights_frag<<<256, 512, 0, stream>>>(W_ih, W_hh, WsumF, WhhF);
    prep_state<<<1088, 256, 0, stream>>>(h, W_out, b_ih, b_hh, hs, Woutp, bperm);
    prep_c<<<1024, 256, 0, stream>>>(c, cbuf);

    // step 0: x = 0 -> W_hh only; steps 1..9: x == h_prev -> fused W_ih + W_hh
    lstm_step<<<dim3(32, 8), 512, DYN_LDS, stream>>>(WhhF, bperm, hs, cbuf,
                                                     hs + (size_t)B_DIM * E_DIM);
    for (int t = 1; t < T_STEPS; ++t)
        lstm_step<<<dim3(32, 8), 512, DYN_LDS, stream>>>(WsumF, bperm,
                                                         hs + (size_t)t * B_DIM * E_DIM,
                                                         cbuf,
                                                         hs + (size_t)(t + 1) * B_DIM * E_DIM);

    proj_kernel<<<dim3(32, T_STEPS), 256, 0, stream>>>(hs + (size_t)B_DIM * E_DIM,
                                                       Woutp, b_out, out);
}